// Round 1
// baseline (354.282 us; speedup 1.0000x reference)
//
#include <hip/hip_runtime.h>

// Problem constants
#define E_DIM 1024
#define H_NUM 16
#define D_HEAD 64
#define SEQ 2048
#define BATCH 2
#define NTOK 4096      // BATCH*SEQ
#define R_LORA 128
#define K1 1152        // E_DIM + R_LORA (concat-K for fused LoRA)
#define Q3 3072        // 3*E_DIM

typedef float floatx4 __attribute__((ext_vector_type(4)));
typedef __bf16 bf16x8 __attribute__((ext_vector_type(8)));
typedef bf16x8 bf16x8_al __attribute__((may_alias));

// async global->LDS, 16B per lane; lds dst must be wave-uniform (HW adds lane*16)
__device__ __forceinline__ void async_cp16(const void* g, void* l) {
  __builtin_amdgcn_global_load_lds(
      (__attribute__((address_space(1))) unsigned int*)(size_t)g,
      (__attribute__((address_space(3))) unsigned int*)l, 16, 0, 0);
}

// ---------------- prep kernels ----------------
__global__ __launch_bounds__(256) void prep_x_kernel(const float* __restrict__ x,
                                                     __bf16* __restrict__ xcat) {
  int idx = (blockIdx.x * 256 + threadIdx.x) * 4;   // over 4096*1024
  int n = idx >> 10, k = idx & 1023;
  const float4 v = *(const float4*)(x + idx);
  __bf16* d = xcat + (size_t)n * K1 + k;
  d[0] = (__bf16)v.x; d[1] = (__bf16)v.y; d[2] = (__bf16)v.z; d[3] = (__bf16)v.w;
}

// Wcat[j][0:1024] = sum of 3 E-blocks of W_in row j ; Wcat[j][1024:1152] = B_in row j
__global__ __launch_bounds__(128) void prep_wcat_kernel(const float* __restrict__ W,
                                                        const float* __restrict__ Bl,
                                                        __bf16* __restrict__ wcat) {
  int e = blockIdx.x * 128 + threadIdx.x;  // 0..1151
  int j = blockIdx.y;                      // 0..3071
  float v;
  if (e < E_DIM) {
    const float* r = W + (size_t)j * Q3;
    v = r[e] + r[e + 1024] + r[e + 2048];
  } else {
    v = Bl[(size_t)j * R_LORA + (e - E_DIM)];
  }
  wcat[(size_t)j * K1 + e] = (__bf16)v;
}

__global__ __launch_bounds__(128) void prep_aeff_kernel(const float* __restrict__ A,
                                                        __bf16* __restrict__ aeff) {
  int e = blockIdx.x * 128 + threadIdx.x;  // 0..1023
  int r = blockIdx.y;                      // 0..127
  const float* rp = A + (size_t)r * Q3;
  aeff[(size_t)r * E_DIM + e] = (__bf16)(rp[e] + rp[e + 1024] + rp[e + 2048]);
}

__global__ __launch_bounds__(256) void prep_wo_kernel(const float* __restrict__ W,
                                                      __bf16* __restrict__ wo) {
  int idx = blockIdx.x * 256 + threadIdx.x;  // 1024*1024
  wo[idx] = (__bf16)W[idx];
}

// ---------------- 128x128 MFMA GEMM: D[m][n] = sum_k A[m][k]*B[n][k] ----------------
// EPI 0: fp32 store, ldc=1024 (out-proj)   EPI 1: qkv scatter to Q/K/V [bh][s][d]
// EPI 2: bf16 store *(1/128) into xcat cols 1024..1151 (LoRA t)
template <int KTOT, int LDA, int LDB, int EPI>
__global__ __launch_bounds__(256) void gemm_mfma(const __bf16* A, const __bf16* Bm,
                                                 float* fOut, __bf16* o0, __bf16* o1,
                                                 __bf16* o2) {
  __shared__ __bf16 lds[8192];  // A-tile 8x(16x32) frag-blocks, then B-tile
  const int t = threadIdx.x;
  const int wave = t >> 6, lane = t & 63;
  const int wm = wave & 1, wn = wave >> 1;
  const int lr = lane & 15, lq = lane >> 4;
  const int m0 = blockIdx.x * 128, n0 = blockIdx.y * 128;

  floatx4 acc[4][4] = {};
  const __bf16* gA = A + (size_t)(m0 + lr) * LDA + lq * 8;
  const __bf16* gB = Bm + (size_t)(n0 + lr) * LDB + lq * 8;

  for (int kk = 0; kk < KTOT; kk += 32) {
    __syncthreads();  // prior frag reads done before overwrite
    async_cp16(gA + (size_t)(wave * 16) * LDA + kk, lds + wave * 512);
    async_cp16(gA + (size_t)((wave + 4) * 16) * LDA + kk, lds + (wave + 4) * 512);
    async_cp16(gB + (size_t)(wave * 16) * LDB + kk, lds + 4096 + wave * 512);
    async_cp16(gB + (size_t)((wave + 4) * 16) * LDB + kk, lds + 4096 + (wave + 4) * 512);
    __syncthreads();  // drains vmcnt -> staging visible
    bf16x8 af[4], bfr[4];
#pragma unroll
    for (int i = 0; i < 4; i++)
      af[i] = *(const bf16x8_al*)(lds + (wm * 4 + i) * 512 + lane * 8);
#pragma unroll
    for (int j = 0; j < 4; j++)
      bfr[j] = *(const bf16x8_al*)(lds + 4096 + (wn * 4 + j) * 512 + lane * 8);
#pragma unroll
    for (int i = 0; i < 4; i++)
#pragma unroll
      for (int j = 0; j < 4; j++)
        acc[i][j] = __builtin_amdgcn_mfma_f32_16x16x32_bf16(af[i], bfr[j], acc[i][j], 0, 0, 0);
  }

#pragma unroll
  for (int i = 0; i < 4; i++)
#pragma unroll
    for (int j = 0; j < 4; j++)
#pragma unroll
      for (int r = 0; r < 4; r++) {
        int row = m0 + wm * 64 + i * 16 + lq * 4 + r;  // C/D: row = quad*4+reg
        int col = n0 + wn * 64 + j * 16 + lr;          // C/D: col = lane&15
        float v = acc[i][j][r];
        if (EPI == 0) {
          fOut[(size_t)row * 1024 + col] = v;
        } else if (EPI == 2) {
          o0[(size_t)row * K1 + E_DIM + col] = (__bf16)(v * (1.0f / 128.0f));
        } else {
          int part = col >> 10, e = col & 1023, h = e >> 6, d = e & 63;
          int b = row >> 11, s = row & 2047;
          size_t off = ((size_t)(b * H_NUM + h) * SEQ + s) * D_HEAD + d;
          __bf16 hv = (__bf16)v;
          if (part == 0) o0[off] = hv;
          else if (part == 1) o1[off] = hv;
          else o2[off] = hv;
        }
      }
}

// ---------------- V transpose: [bh][s][d] -> [bh][d][s] ----------------
__global__ __launch_bounds__(256) void transpose_v_kernel(const __bf16* __restrict__ V,
                                                          __bf16* __restrict__ Vt) {
  __shared__ __bf16 tile[64][65];
  int bh = blockIdx.y, s0 = blockIdx.x * 64;
  int t = threadIdx.x;
  int c = t & 63, r4 = t >> 6;
  const __bf16* src = V + ((size_t)bh * SEQ + s0) * D_HEAD;
#pragma unroll
  for (int i = 0; i < 16; i++) {
    int s = r4 + i * 4;
    tile[s][c] = src[(size_t)s * D_HEAD + c];
  }
  __syncthreads();
  __bf16* dst = Vt + (size_t)bh * D_HEAD * SEQ + s0;
#pragma unroll
  for (int i = 0; i < 16; i++) {
    int d = r4 + i * 4;
    dst[(size_t)d * SEQ + c] = tile[c][d];
  }
}

// ---------------- flash attention: 64 q-rows/block (16/wave), 128-key tiles ----------------
__global__ __launch_bounds__(256) void attn_kernel(const __bf16* __restrict__ Q,
                                                   const __bf16* __restrict__ K,
                                                   const __bf16* __restrict__ Vt,
                                                   __bf16* __restrict__ O) {
  __shared__ __bf16 kls[8192];        // K-tile 128x64 frag-order (16 blocks of 1KB)
  __shared__ __bf16 vls[8192];        // Vt-tile 64x128 frag-order
  __shared__ __bf16 pls[4][16 * 136]; // per-wave P 16x128, stride 136 (16B aligned, banks OK)
  const int t = threadIdx.x, wave = t >> 6, lane = t & 63;
  const int lr = lane & 15, lq = lane >> 4;
  const int bh = blockIdx.y, q0 = blockIdx.x * 64;
  const size_t hbase = (size_t)bh * SEQ * D_HEAD;
  const __bf16* vtb = Vt + (size_t)bh * D_HEAD * SEQ;

  bf16x8 qf0, qf1;  // Q A-frags, loaded once (rows q0+wave*16+lr)
  {
    const __bf16* qp = Q + hbase + (size_t)(q0 + wave * 16 + lr) * D_HEAD + lq * 8;
    qf0 = *(const bf16x8_al*)qp;
    qf1 = *(const bf16x8_al*)(qp + 32);
  }
  floatx4 oacc[4] = {};
  float m_i[4], l_i[4];
#pragma unroll
  for (int r = 0; r < 4; r++) { m_i[r] = -1e30f; l_i[r] = 0.0f; }
  const float scale = 0.125f;  // 1/sqrt(64)

  for (int kt = 0; kt < SEQ; kt += 128) {
#pragma unroll
    for (int ii = 0; ii < 4; ii++) {
      int b = wave * 4 + ii;        // 16 K-blocks: (key16 kb, d-chunk c)
      int kb = b >> 1, c = b & 1;
      async_cp16(K + hbase + (size_t)(kt + kb * 16 + lr) * D_HEAD + c * 32 + lq * 8,
                 kls + b * 512);
      int dg = b >> 2, kc = b & 3;  // 16 Vt-blocks: (d16 dg, key-chunk kc)
      async_cp16(vtb + (size_t)(dg * 16 + lr) * SEQ + kt + kc * 32 + lq * 8,
                 vls + b * 512);
    }
    __syncthreads();

    // S = Q @ K^T : rows = quad*4+r (local q), cols = j*16+lr (local key)
    floatx4 sacc[8] = {};
#pragma unroll
    for (int j = 0; j < 8; j++) {
      bf16x8 kf0 = *(const bf16x8_al*)(kls + (j * 2) * 512 + lane * 8);
      bf16x8 kf1 = *(const bf16x8_al*)(kls + (j * 2 + 1) * 512 + lane * 8);
      sacc[j] = __builtin_amdgcn_mfma_f32_16x16x32_bf16(qf0, kf0, sacc[j], 0, 0, 0);
      sacc[j] = __builtin_amdgcn_mfma_f32_16x16x32_bf16(qf1, kf1, sacc[j], 0, 0, 0);
    }

    // online softmax (scale folded into exp argument)
#pragma unroll
    for (int r = 0; r < 4; r++) {
      float mv = sacc[0][r];
#pragma unroll
      for (int j = 1; j < 8; j++) mv = fmaxf(mv, sacc[j][r]);
      mv = fmaxf(mv, __shfl_xor(mv, 1));
      mv = fmaxf(mv, __shfl_xor(mv, 2));
      mv = fmaxf(mv, __shfl_xor(mv, 4));
      mv = fmaxf(mv, __shfl_xor(mv, 8));
      float mnew = fmaxf(m_i[r], mv);
      float al = __expf((m_i[r] - mnew) * scale);
      m_i[r] = mnew;
      float ssum = 0.0f;
#pragma unroll
      for (int j = 0; j < 8; j++) {
        float p = __expf((sacc[j][r] - mnew) * scale);
        ssum += p;
        pls[wave][(lq * 4 + r) * 136 + j * 16 + lr] = (__bf16)p;
      }
      ssum += __shfl_xor(ssum, 1);
      ssum += __shfl_xor(ssum, 2);
      ssum += __shfl_xor(ssum, 4);
      ssum += __shfl_xor(ssum, 8);
      l_i[r] = l_i[r] * al + ssum;
#pragma unroll
      for (int jd = 0; jd < 4; jd++) oacc[jd][r] *= al;
    }

    // O += P @ V  (P via LDS round-trip into A-layout; Vt blocks are B-layout)
#pragma unroll
    for (int kc = 0; kc < 4; kc++) {
      bf16x8 pf = *(const bf16x8_al*)(&pls[wave][lr * 136 + kc * 32 + lq * 8]);
#pragma unroll
      for (int jd = 0; jd < 4; jd++) {
        bf16x8 vf = *(const bf16x8_al*)(vls + (jd * 4 + kc) * 512 + lane * 8);
        oacc[jd] = __builtin_amdgcn_mfma_f32_16x16x32_bf16(pf, vf, oacc[jd], 0, 0, 0);
      }
    }
    __syncthreads();  // reads done before next tile's staging
  }

  const int b = bh >> 4, h = bh & 15;
#pragma unroll
  for (int jd = 0; jd < 4; jd++)
#pragma unroll
    for (int r = 0; r < 4; r++) {
      int s = q0 + wave * 16 + lq * 4 + r;
      int d = jd * 16 + lr;
      float v = oacc[jd][r] / l_i[r];
      O[((size_t)b * SEQ + s) * E_DIM + h * D_HEAD + d] = (__bf16)v;
    }
}

// ---------------- launch ----------------
extern "C" void kernel_launch(void* const* d_in, const int* in_sizes, int n_in,
                              void* d_out, int out_size, void* d_ws, size_t ws_size,
                              hipStream_t stream) {
  const float* x  = (const float*)d_in[0];
  const float* Wi = (const float*)d_in[1];
  const float* Ai = (const float*)d_in[2];
  const float* Bi = (const float*)d_in[3];
  const float* Wo = (const float*)d_in[4];
  float* out = (float*)d_out;
  char* ws = (char*)d_ws;

  // workspace layout (bytes), total ~61 MB
  __bf16* xcat = (__bf16*)(ws);                  //  4096x1152 bf16   9,437,184
  __bf16* wcat = (__bf16*)(ws + 9437184);        //  3072x1152 bf16   7,077,888
  __bf16* aeff = (__bf16*)(ws + 16515072);       //  128x1024 bf16      262,144
  __bf16* wob  = (__bf16*)(ws + 16777216);       //  1024x1024 bf16   2,097,152
  __bf16* qh   = (__bf16*)(ws + 18874368);       //  [32][2048][64]   8,388,608
  __bf16* kh   = (__bf16*)(ws + 27262976);       //  [32][2048][64]   8,388,608
  __bf16* vh   = (__bf16*)(ws + 35651584);       //  [32][2048][64]   8,388,608
  __bf16* vt   = (__bf16*)(ws + 44040192);       //  [32][64][2048]   8,388,608
  __bf16* oh   = (__bf16*)(ws + 52428800);       //  4096x1024 bf16   8,388,608

  prep_x_kernel<<<4096, 256, 0, stream>>>(x, xcat);
  prep_wcat_kernel<<<dim3(9, 3072), 128, 0, stream>>>(Wi, Bi, wcat);
  prep_aeff_kernel<<<dim3(8, 128), 128, 0, stream>>>(Ai, aeff);
  prep_wo_kernel<<<4096, 256, 0, stream>>>(Wo, wob);

  // t = (x @ Aeff^T)/128 -> xcat cols 1024..1151
  gemm_mfma<1024, K1, E_DIM, 2><<<dim3(32, 1), 256, 0, stream>>>(
      xcat, aeff, nullptr, xcat, nullptr, nullptr);
  // qkv = xcat @ Wcat^T, scattered to Q/K/V head layout
  gemm_mfma<K1, K1, K1, 1><<<dim3(32, 24), 256, 0, stream>>>(
      xcat, wcat, nullptr, qh, kh, vh);
  transpose_v_kernel<<<dim3(32, 32), 256, 0, stream>>>(vh, vt);
  attn_kernel<<<dim3(32, 32), 256, 0, stream>>>(qh, kh, vt, oh);
  // final = O @ Wo^T (fp32 out)
  gemm_mfma<1024, 1024, 1024, 0><<<dim3(32, 8), 256, 0, stream>>>(
      oh, wob, out, nullptr, nullptr, nullptr);
}

// Round 3
// 279.678 us; speedup vs baseline: 1.2667x; 1.2667x over previous
//
#include <hip/hip_runtime.h>

// Problem constants
#define E_DIM 1024
#define H_NUM 16
#define D_HEAD 64
#define SEQ 2048
#define BATCH 2
#define NTOK 4096      // BATCH*SEQ
#define R_LORA 128
#define K1 1152        // E_DIM + R_LORA (concat-K for fused LoRA)
#define Q3 3072        // 3*E_DIM
#define K_PRESCALE 0.125f  // 1/sqrt(64), exact in bf16

typedef float floatx4 __attribute__((ext_vector_type(4)));
typedef __bf16 bf16x8 __attribute__((ext_vector_type(8)));
typedef __bf16 bf16x4 __attribute__((ext_vector_type(4)));
typedef bf16x8 bf16x8_al __attribute__((may_alias));
typedef bf16x4 bf16x4_al __attribute__((may_alias));

// async global->LDS, 16B per lane; lds dst must be wave-uniform (HW adds lane*16)
__device__ __forceinline__ void async_cp16(const void* g, void* l) {
  __builtin_amdgcn_global_load_lds(
      (__attribute__((address_space(1))) unsigned int*)(size_t)g,
      (__attribute__((address_space(3))) unsigned int*)l, 16, 0, 0);
}

// ---------------- fused prep kernel (one launch) ----------------
// block ranges: [0,4096) x->xcat | [4096,7168) wcat main | [7168,7552) wcat lora
//               [7552,7680) aeff | [7680,8704) wo
__global__ __launch_bounds__(256) void prep_all(const float* __restrict__ x,
                                                const float* __restrict__ Wi,
                                                const float* __restrict__ Bl,
                                                const float* __restrict__ Ai,
                                                const float* __restrict__ Wo,
                                                __bf16* __restrict__ xcat,
                                                __bf16* __restrict__ wcat,
                                                __bf16* __restrict__ aeff,
                                                __bf16* __restrict__ wob) {
  const int blk = blockIdx.x, t = threadIdx.x;
  if (blk < 4096) {                       // x (4096x1024 fp32) -> xcat cols 0..1023
    int idx = (blk * 256 + t) * 4;
    int n = idx >> 10, k = idx & 1023;
    float4 v = *(const float4*)(x + idx);
    bf16x4 o = {(__bf16)v.x, (__bf16)v.y, (__bf16)v.z, (__bf16)v.w};
    *(bf16x4_al*)(xcat + (size_t)n * K1 + k) = o;
  } else if (blk < 7168) {                // wcat main: row j, fold 3 E-blocks of W_in
    int j = blk - 4096, e = t * 4;
    const float* r = Wi + (size_t)j * Q3;
    float4 a = *(const float4*)(r + e);
    float4 b = *(const float4*)(r + e + 1024);
    float4 c = *(const float4*)(r + e + 2048);
    bf16x4 o = {(__bf16)(a.x + b.x + c.x), (__bf16)(a.y + b.y + c.y),
                (__bf16)(a.z + b.z + c.z), (__bf16)(a.w + b.w + c.w)};
    *(bf16x4_al*)(wcat + (size_t)j * K1 + e) = o;
  } else if (blk < 7552) {                // wcat lora cols: B_in rows
    int idx = (blk - 7168) * 256 + t;     // quad id over 3072x32
    int j = idx >> 5, cq = (idx & 31) * 4;
    float4 v = *(const float4*)(Bl + (size_t)j * R_LORA + cq);
    bf16x4 o = {(__bf16)v.x, (__bf16)v.y, (__bf16)v.z, (__bf16)v.w};
    *(bf16x4_al*)(wcat + (size_t)j * K1 + E_DIM + cq) = o;
  } else if (blk < 7680) {                // aeff: fold 3 E-blocks of A_in
    int r = blk - 7552, e = t * 4;
    const float* rp = Ai + (size_t)r * Q3;
    float4 a = *(const float4*)(rp + e);
    float4 b = *(const float4*)(rp + e + 1024);
    float4 c = *(const float4*)(rp + e + 2048);
    bf16x4 o = {(__bf16)(a.x + b.x + c.x), (__bf16)(a.y + b.y + c.y),
                (__bf16)(a.z + b.z + c.z), (__bf16)(a.w + b.w + c.w)};
    *(bf16x4_al*)(aeff + (size_t)r * E_DIM + e) = o;
  } else {                                // wo cast
    int idx = ((blk - 7680) * 256 + t) * 4;
    float4 v = *(const float4*)(Wo + idx);
    bf16x4 o = {(__bf16)v.x, (__bf16)v.y, (__bf16)v.z, (__bf16)v.w};
    *(bf16x4_al*)(wob + idx) = o;
  }
}

// ---------------- 128x128 MFMA GEMM: D[m][n] = sum_k A[m][k]*B[n][k] ----------------
// EPI 0: fp32 store, ldc=1024 (out-proj)   EPI 1: qkv scatter to Q/K/V [bh][s][d]
//        (K part pre-scaled by 0.125 so attention skips the softmax scale)
// EPI 2: bf16 store *(1/128) into xcat cols 1024..1151 (LoRA t)
template <int KTOT, int LDA, int LDB, int EPI>
__global__ __launch_bounds__(256) void gemm_mfma(const __bf16* A, const __bf16* Bm,
                                                 float* fOut, __bf16* o0, __bf16* o1,
                                                 __bf16* o2) {
  __shared__ __bf16 lds[8192];  // A-tile 8x(16x32) frag-blocks, then B-tile
  const int t = threadIdx.x;
  const int wave = t >> 6, lane = t & 63;
  const int wm = wave & 1, wn = wave >> 1;
  const int lr = lane & 15, lq = lane >> 4;
  const int m0 = blockIdx.x * 128, n0 = blockIdx.y * 128;

  floatx4 acc[4][4] = {};
  const __bf16* gA = A + (size_t)(m0 + lr) * LDA + lq * 8;
  const __bf16* gB = Bm + (size_t)(n0 + lr) * LDB + lq * 8;

  for (int kk = 0; kk < KTOT; kk += 32) {
    __syncthreads();  // prior frag reads done before overwrite
    async_cp16(gA + (size_t)(wave * 16) * LDA + kk, lds + wave * 512);
    async_cp16(gA + (size_t)((wave + 4) * 16) * LDA + kk, lds + (wave + 4) * 512);
    async_cp16(gB + (size_t)(wave * 16) * LDB + kk, lds + 4096 + wave * 512);
    async_cp16(gB + (size_t)((wave + 4) * 16) * LDB + kk, lds + 4096 + (wave + 4) * 512);
    __syncthreads();  // drains vmcnt -> staging visible
    bf16x8 af[4], bfr[4];
#pragma unroll
    for (int i = 0; i < 4; i++)
      af[i] = *(const bf16x8_al*)(lds + (wm * 4 + i) * 512 + lane * 8);
#pragma unroll
    for (int j = 0; j < 4; j++)
      bfr[j] = *(const bf16x8_al*)(lds + 4096 + (wn * 4 + j) * 512 + lane * 8);
#pragma unroll
    for (int i = 0; i < 4; i++)
#pragma unroll
      for (int j = 0; j < 4; j++)
        acc[i][j] = __builtin_amdgcn_mfma_f32_16x16x32_bf16(af[i], bfr[j], acc[i][j], 0, 0, 0);
  }

#pragma unroll
  for (int i = 0; i < 4; i++)
#pragma unroll
    for (int j = 0; j < 4; j++)
#pragma unroll
      for (int r = 0; r < 4; r++) {
        int row = m0 + wm * 64 + i * 16 + lq * 4 + r;  // C/D: row = quad*4+reg
        int col = n0 + wn * 64 + j * 16 + lr;          // C/D: col = lane&15
        float v = acc[i][j][r];
        if (EPI == 0) {
          fOut[(size_t)row * 1024 + col] = v;
        } else if (EPI == 2) {
          o0[(size_t)row * K1 + E_DIM + col] = (__bf16)(v * (1.0f / 128.0f));
        } else {
          int part = col >> 10, e = col & 1023, h = e >> 6, d = e & 63;
          int b = row >> 11, s = row & 2047;
          size_t off = ((size_t)(b * H_NUM + h) * SEQ + s) * D_HEAD + d;
          if (part == 1) v *= K_PRESCALE;  // fold softmax 1/sqrt(D) into K
          __bf16 hv = (__bf16)v;
          if (part == 0) o0[off] = hv;
          else if (part == 1) o1[off] = hv;
          else o2[off] = hv;
        }
      }
}

// ---------------- V transpose: [bh][s][d] -> [bh][d][s] ----------------
__global__ __launch_bounds__(256) void transpose_v_kernel(const __bf16* __restrict__ V,
                                                          __bf16* __restrict__ Vt) {
  __shared__ __bf16 tile[64][65];
  int bh = blockIdx.y, s0 = blockIdx.x * 64;
  int t = threadIdx.x;
  int c = t & 63, r4 = t >> 6;
  const __bf16* src = V + ((size_t)bh * SEQ + s0) * D_HEAD;
#pragma unroll
  for (int i = 0; i < 16; i++) {
    int s = r4 + i * 4;
    tile[s][c] = src[(size_t)s * D_HEAD + c];
  }
  __syncthreads();
  __bf16* dst = Vt + (size_t)bh * D_HEAD * SEQ + s0;
#pragma unroll
  for (int i = 0; i < 16; i++) {
    int d = r4 + i * 4;
    dst[(size_t)d * SEQ + c] = tile[c][d];
  }
}

// ---------------- flash attention v3 ----------------
// 64 q-rows/block (16/wave). 64-key tiles, SINGLE-buffer LDS, proven two-barrier
// staging (m97 pattern). S^T = K x Q via MFMA (keys=rows) so each lane holds 4
// consecutive keys for one q -> P^T store is one ds_write_b64; PV reads P as
// A-frag via XOR-swizzled chunks. Max-free softmax: K pre-scaled by 1/8,
// p = __expf(s), l summed per-lane, reduced once at the end.
__global__ __launch_bounds__(256, 4) void attn_kernel(const __bf16* __restrict__ Q,
                                                      const __bf16* __restrict__ K,
                                                      const __bf16* __restrict__ Vt,
                                                      __bf16* __restrict__ O) {
  __shared__ __bf16 smem[4096 + 4096 + 4096];  // kls[8][512] | vls[8][512] | pls[4][1024]
  __bf16* kls = smem;
  __bf16* vls = smem + 4096;
  const int t = threadIdx.x, wave = t >> 6, lane = t & 63;
  const int lr = lane & 15, lq = lane >> 4;
  __bf16* plsw = smem + 8192 + wave * 1024;  // per-wave P: [q=16][key=64], XOR-swizzled chunks
  const int bh = blockIdx.y, q0 = blockIdx.x * 64;
  const size_t hbase = (size_t)bh * SEQ * D_HEAD;
  const __bf16* Kp = K + hbase;
  const __bf16* vtb = Vt + (size_t)bh * D_HEAD * SEQ;
  const int row7 = lr & 7;

  // Q frags (B-operand: rows q = q0+wave*16+lr)
  bf16x8 qf0, qf1;
  {
    const __bf16* qp = Q + hbase + (size_t)(q0 + wave * 16 + lr) * D_HEAD + lq * 8;
    qf0 = *(const bf16x8_al*)qp;
    qf1 = *(const bf16x8_al*)(qp + 32);
  }

  floatx4 oacc[4] = {};
  float lsum = 0.0f;

  for (int kt = 0; kt < SEQ; kt += 64) {
    __syncthreads();  // prior tile's LDS reads complete before overwrite
    // stage 16 blocks: 0..7 = K (kb=s>>1, c=s&1), 8..15 = V (dg, kc)
#pragma unroll
    for (int ii = 0; ii < 4; ii++) {
      int s = wave * 4 + ii;
      const __bf16* src;
      if (s < 8) {
        src = Kp + (size_t)(kt + (s >> 1) * 16 + lr) * D_HEAD + (s & 1) * 32 + lq * 8;
      } else {
        int v = s - 8;
        src = vtb + (size_t)((v >> 1) * 16 + lr) * SEQ + kt + (v & 1) * 32 + lq * 8;
      }
      async_cp16(src, smem + s * 512);
    }
    __syncthreads();  // drains vmcnt -> staging visible

    // S^T (keys x q) + softmax + P^T pack
#pragma unroll
    for (int kb = 0; kb < 4; kb++) {
      bf16x8 kf0 = *(const bf16x8_al*)(kls + (kb * 2) * 512 + lane * 8);
      bf16x8 kf1 = *(const bf16x8_al*)(kls + (kb * 2 + 1) * 512 + lane * 8);
      floatx4 s = {};
      s = __builtin_amdgcn_mfma_f32_16x16x32_bf16(kf0, qf0, s, 0, 0, 0);
      s = __builtin_amdgcn_mfma_f32_16x16x32_bf16(kf1, qf1, s, 0, 0, 0);
      bf16x4 pv;
#pragma unroll
      for (int r = 0; r < 4; r++) {
        float p = __expf(s[r]);  // 1/sqrt(D) already folded into K
        lsum += p;
        pv[r] = (__bf16)p;
      }
      // lane holds keys kb*16+lq*4+{0..3} for q=lr -> one b64 store
      int chunk = (kb * 2 + (lq >> 1)) ^ row7;
      *(bf16x4_al*)(plsw + lr * 64 + chunk * 8 + (lq & 1) * 4) = pv;
    }

    // O += P @ V : A-frag P[q=lr][key=kc*32+lq*8+j], B-frag Vt[d][key]
#pragma unroll
    for (int kc = 0; kc < 2; kc++) {
      int chunk = (kc * 4 + lq) ^ row7;
      bf16x8 pf = *(const bf16x8_al*)(plsw + lr * 64 + chunk * 8);
#pragma unroll
      for (int jd = 0; jd < 4; jd++) {
        bf16x8 vf = *(const bf16x8_al*)(vls + (jd * 2 + kc) * 512 + lane * 8);
        oacc[jd] = __builtin_amdgcn_mfma_f32_16x16x32_bf16(pf, vf, oacc[jd], 0, 0, 0);
      }
    }
  }

  // reduce l across the 4 lanes sharing q=lr (lq groups)
  lsum += __shfl_xor(lsum, 16);
  lsum += __shfl_xor(lsum, 32);

  const int b = bh >> 4, h = bh & 15;
#pragma unroll
  for (int r = 0; r < 4; r++) {
    float linv = 1.0f / __shfl(lsum, lq * 4 + r);  // lane q_local holds l(q_local)
    int s = q0 + wave * 16 + lq * 4 + r;
#pragma unroll
    for (int jd = 0; jd < 4; jd++) {
      int d = jd * 16 + lr;
      O[((size_t)b * SEQ + s) * E_DIM + h * D_HEAD + d] = (__bf16)(oacc[jd][r] * linv);
    }
  }
}

// ---------------- launch ----------------
extern "C" void kernel_launch(void* const* d_in, const int* in_sizes, int n_in,
                              void* d_out, int out_size, void* d_ws, size_t ws_size,
                              hipStream_t stream) {
  const float* x  = (const float*)d_in[0];
  const float* Wi = (const float*)d_in[1];
  const float* Ai = (const float*)d_in[2];
  const float* Bi = (const float*)d_in[3];
  const float* Wo = (const float*)d_in[4];
  float* out = (float*)d_out;
  char* ws = (char*)d_ws;

  // workspace layout (bytes), total ~61 MB
  __bf16* xcat = (__bf16*)(ws);                  //  4096x1152 bf16   9,437,184
  __bf16* wcat = (__bf16*)(ws + 9437184);        //  3072x1152 bf16   7,077,888
  __bf16* aeff = (__bf16*)(ws + 16515072);       //  128x1024 bf16      262,144
  __bf16* wob  = (__bf16*)(ws + 16777216);       //  1024x1024 bf16   2,097,152
  __bf16* qh   = (__bf16*)(ws + 18874368);       //  [32][2048][64]   8,388,608
  __bf16* kh   = (__bf16*)(ws + 27262976);       //  [32][2048][64]   8,388,608
  __bf16* vh   = (__bf16*)(ws + 35651584);       //  [32][2048][64]   8,388,608
  __bf16* vt   = (__bf16*)(ws + 44040192);       //  [32][64][2048]   8,388,608
  __bf16* oh   = (__bf16*)(ws + 52428800);       //  4096x1024 bf16   8,388,608

  prep_all<<<8704, 256, 0, stream>>>(x, Wi, Bi, Ai, Wo, xcat, wcat, aeff, wob);

  // t = (x @ Aeff^T)/128 -> xcat cols 1024..1151
  gemm_mfma<1024, K1, E_DIM, 2><<<dim3(32, 1), 256, 0, stream>>>(
      xcat, aeff, nullptr, xcat, nullptr, nullptr);
  // qkv = xcat @ Wcat^T, scattered to Q/K/V head layout (K pre-scaled by 1/8)
  gemm_mfma<K1, K1, K1, 1><<<dim3(32, 24), 256, 0, stream>>>(
      xcat, wcat, nullptr, qh, kh, vh);
  transpose_v_kernel<<<dim3(32, 32), 256, 0, stream>>>(vh, vt);
  attn_kernel<<<dim3(32, 32), 256, 0, stream>>>(qh, kh, vt, oh);
  // final = O @ Wo^T (fp32 out)
  gemm_mfma<1024, 1024, 1024, 0><<<dim3(32, 8), 256, 0, stream>>>(
      oh, wob, out, nullptr, nullptr, nullptr);
}

// Round 4
// 279.318 us; speedup vs baseline: 1.2684x; 1.0013x over previous
//
#include <hip/hip_runtime.h>

// Problem constants
#define E_DIM 1024
#define H_NUM 16
#define D_HEAD 64
#define SEQ 2048
#define BATCH 2
#define NTOK 4096      // BATCH*SEQ
#define R_LORA 128
#define K1 1152        // E_DIM + R_LORA (concat-K for fused LoRA)
#define Q3 3072        // 3*E_DIM
#define K_PRESCALE 0.125f  // 1/sqrt(64), exact in bf16

typedef float floatx4 __attribute__((ext_vector_type(4)));
typedef __bf16 bf16x8 __attribute__((ext_vector_type(8)));
typedef __bf16 bf16x4 __attribute__((ext_vector_type(4)));
typedef bf16x8 bf16x8_al __attribute__((may_alias));
typedef bf16x4 bf16x4_al __attribute__((may_alias));

// async global->LDS, 16B per lane; lds dst must be wave-uniform (HW adds lane*16)
__device__ __forceinline__ void async_cp16(const void* g, void* l) {
  __builtin_amdgcn_global_load_lds(
      (__attribute__((address_space(1))) unsigned int*)(size_t)g,
      (__attribute__((address_space(3))) unsigned int*)l, 16, 0, 0);
}

// ---------------- fused prep kernel (one launch) ----------------
// block ranges: [0,4096) x->xcat | [4096,7168) wcat main | [7168,7552) wcat lora
//               [7552,7680) aeff | [7680,8704) wo
__global__ __launch_bounds__(256) void prep_all(const float* __restrict__ x,
                                                const float* __restrict__ Wi,
                                                const float* __restrict__ Bl,
                                                const float* __restrict__ Ai,
                                                const float* __restrict__ Wo,
                                                __bf16* __restrict__ xcat,
                                                __bf16* __restrict__ wcat,
                                                __bf16* __restrict__ aeff,
                                                __bf16* __restrict__ wob) {
  const int blk = blockIdx.x, t = threadIdx.x;
  if (blk < 4096) {                       // x (4096x1024 fp32) -> xcat cols 0..1023
    int idx = (blk * 256 + t) * 4;
    int n = idx >> 10, k = idx & 1023;
    float4 v = *(const float4*)(x + idx);
    bf16x4 o = {(__bf16)v.x, (__bf16)v.y, (__bf16)v.z, (__bf16)v.w};
    *(bf16x4_al*)(xcat + (size_t)n * K1 + k) = o;
  } else if (blk < 7168) {                // wcat main: row j, fold 3 E-blocks of W_in
    int j = blk - 4096, e = t * 4;
    const float* r = Wi + (size_t)j * Q3;
    float4 a = *(const float4*)(r + e);
    float4 b = *(const float4*)(r + e + 1024);
    float4 c = *(const float4*)(r + e + 2048);
    bf16x4 o = {(__bf16)(a.x + b.x + c.x), (__bf16)(a.y + b.y + c.y),
                (__bf16)(a.z + b.z + c.z), (__bf16)(a.w + b.w + c.w)};
    *(bf16x4_al*)(wcat + (size_t)j * K1 + e) = o;
  } else if (blk < 7552) {                // wcat lora cols: B_in rows
    int idx = (blk - 7168) * 256 + t;     // quad id over 3072x32
    int j = idx >> 5, cq = (idx & 31) * 4;
    float4 v = *(const float4*)(Bl + (size_t)j * R_LORA + cq);
    bf16x4 o = {(__bf16)v.x, (__bf16)v.y, (__bf16)v.z, (__bf16)v.w};
    *(bf16x4_al*)(wcat + (size_t)j * K1 + E_DIM + cq) = o;
  } else if (blk < 7680) {                // aeff: fold 3 E-blocks of A_in
    int r = blk - 7552, e = t * 4;
    const float* rp = Ai + (size_t)r * Q3;
    float4 a = *(const float4*)(rp + e);
    float4 b = *(const float4*)(rp + e + 1024);
    float4 c = *(const float4*)(rp + e + 2048);
    bf16x4 o = {(__bf16)(a.x + b.x + c.x), (__bf16)(a.y + b.y + c.y),
                (__bf16)(a.z + b.z + c.z), (__bf16)(a.w + b.w + c.w)};
    *(bf16x4_al*)(aeff + (size_t)r * E_DIM + e) = o;
  } else {                                // wo cast
    int idx = ((blk - 7680) * 256 + t) * 4;
    float4 v = *(const float4*)(Wo + idx);
    bf16x4 o = {(__bf16)v.x, (__bf16)v.y, (__bf16)v.z, (__bf16)v.w};
    *(bf16x4_al*)(wob + idx) = o;
  }
}

// ---------------- 128x128 MFMA GEMM: D[m][n] = sum_k A[m][k]*B[n][k] ----------------
// EPI 0: fp32 store, ldc=1024 (out-proj)
// EPI 1: qkv scatter; Q,K -> [bh][s][d] scalar (K pre-scaled by 0.125);
//        V -> V^T [bh][d][s] as packed bf16x4 (transpose fused here)
// EPI 2: bf16 store *(1/128) into xcat cols 1024..1151 (LoRA t)
template <int KTOT, int LDA, int LDB, int EPI>
__global__ __launch_bounds__(256) void gemm_mfma(const __bf16* A, const __bf16* Bm,
                                                 float* fOut, __bf16* o0, __bf16* o1,
                                                 __bf16* o2) {
  __shared__ __bf16 lds[8192];  // A-tile 8x(16x32) frag-blocks, then B-tile
  const int t = threadIdx.x;
  const int wave = t >> 6, lane = t & 63;
  const int wm = wave & 1, wn = wave >> 1;
  const int lr = lane & 15, lq = lane >> 4;
  const int m0 = blockIdx.x * 128, n0 = blockIdx.y * 128;

  floatx4 acc[4][4] = {};
  const __bf16* gA = A + (size_t)(m0 + lr) * LDA + lq * 8;
  const __bf16* gB = Bm + (size_t)(n0 + lr) * LDB + lq * 8;

  for (int kk = 0; kk < KTOT; kk += 32) {
    __syncthreads();  // prior frag reads done before overwrite
    async_cp16(gA + (size_t)(wave * 16) * LDA + kk, lds + wave * 512);
    async_cp16(gA + (size_t)((wave + 4) * 16) * LDA + kk, lds + (wave + 4) * 512);
    async_cp16(gB + (size_t)(wave * 16) * LDB + kk, lds + 4096 + wave * 512);
    async_cp16(gB + (size_t)((wave + 4) * 16) * LDB + kk, lds + 4096 + (wave + 4) * 512);
    __syncthreads();  // drains vmcnt -> staging visible
    bf16x8 af[4], bfr[4];
#pragma unroll
    for (int i = 0; i < 4; i++)
      af[i] = *(const bf16x8_al*)(lds + (wm * 4 + i) * 512 + lane * 8);
#pragma unroll
    for (int j = 0; j < 4; j++)
      bfr[j] = *(const bf16x8_al*)(lds + 4096 + (wn * 4 + j) * 512 + lane * 8);
#pragma unroll
    for (int i = 0; i < 4; i++)
#pragma unroll
      for (int j = 0; j < 4; j++)
        acc[i][j] = __builtin_amdgcn_mfma_f32_16x16x32_bf16(af[i], bfr[j], acc[i][j], 0, 0, 0);
  }

#pragma unroll
  for (int i = 0; i < 4; i++)
#pragma unroll
    for (int j = 0; j < 4; j++) {
      const int row0 = m0 + wm * 64 + i * 16 + lq * 4;  // C/D: row = quad*4+reg
      const int col = n0 + wn * 64 + j * 16 + lr;       // C/D: col = lane&15
      if (EPI == 0) {
#pragma unroll
        for (int r = 0; r < 4; r++)
          fOut[(size_t)(row0 + r) * 1024 + col] = acc[i][j][r];
      } else if (EPI == 2) {
#pragma unroll
        for (int r = 0; r < 4; r++)
          o0[(size_t)(row0 + r) * K1 + E_DIM + col] = (__bf16)(acc[i][j][r] * (1.0f / 128.0f));
      } else {
        int part = col >> 10, e = col & 1023, h = e >> 6, d = e & 63;
        int b = row0 >> 11, s = row0 & 2047;
        if (part == 2) {
          // V^T [bh][d][s]: 4 consecutive s in one lane -> packed b64 store
          bf16x4 pv;
#pragma unroll
          for (int r = 0; r < 4; r++) pv[r] = (__bf16)acc[i][j][r];
          *(bf16x4_al*)(o2 + ((size_t)(b * H_NUM + h) * D_HEAD + d) * SEQ + s) = pv;
        } else {
#pragma unroll
          for (int r = 0; r < 4; r++) {
            float v = acc[i][j][r];
            if (part == 1) v *= K_PRESCALE;  // fold softmax 1/sqrt(D) into K
            size_t off = ((size_t)(b * H_NUM + h) * SEQ + (s + r)) * D_HEAD + d;
            (part == 0 ? o0 : o1)[off] = (__bf16)v;
          }
        }
      }
    }
}

// ---------------- flash attention v4: software-pipelined ----------------
// 64 q-rows/block (16/wave). 64-key tiles, DOUBLE-buffered K/V LDS.
// Per tile: issue stage(t+1,buf^1); s_waitcnt vmcnt(4) (waits only tile t's 4
// loads; t+1's stay in flight); raw s_barrier; compute(buf); lgkmcnt(0)+raw
// s_barrier (WAR protect, no vmcnt drain). Compute body identical to proven v3.
__global__ __launch_bounds__(256, 4) void attn_kernel(const __bf16* __restrict__ Q,
                                                      const __bf16* __restrict__ K,
                                                      const __bf16* __restrict__ Vt,
                                                      __bf16* __restrict__ O) {
  __shared__ __bf16 smem[8192 + 8192 + 4096];  // kls[2][4096] | vls[2][4096] | pls[4][1024]
  __bf16* kls = smem;
  __bf16* vls = smem + 8192;
  const int t = threadIdx.x, wave = t >> 6, lane = t & 63;
  const int lr = lane & 15, lq = lane >> 4;
  __bf16* plsw = smem + 16384 + wave * 1024;  // per-wave P: [q=16][key=64], XOR-swizzled chunks
  const int bh = blockIdx.y, q0 = blockIdx.x * 64;
  const size_t hbase = (size_t)bh * SEQ * D_HEAD;
  const __bf16* Kp = K + hbase;
  const __bf16* vtb = Vt + (size_t)bh * D_HEAD * SEQ;
  const int row7 = lr & 7;

  // Q frags (B-operand: rows q = q0+wave*16+lr)
  bf16x8 qf0, qf1;
  {
    const __bf16* qp = Q + hbase + (size_t)(q0 + wave * 16 + lr) * D_HEAD + lq * 8;
    qf0 = *(const bf16x8_al*)qp;
    qf1 = *(const bf16x8_al*)(qp + 32);
  }

  floatx4 oacc[4] = {};
  float lsum = 0.0f;

  // stage one 64-key tile (4 async loads per wave): waves 0,1 -> K, waves 2,3 -> V
  auto stage = [&](int kt, int b) {
#pragma unroll
    for (int ii = 0; ii < 4; ii++) {
      int s = wave * 4 + ii;
      if (s < 8) {
        const __bf16* src =
            Kp + (size_t)(kt + (s >> 1) * 16 + lr) * D_HEAD + (s & 1) * 32 + lq * 8;
        async_cp16(src, kls + b * 4096 + s * 512);
      } else {
        int v = s - 8;
        const __bf16* src =
            vtb + (size_t)((v >> 1) * 16 + lr) * SEQ + kt + (v & 1) * 32 + lq * 8;
        async_cp16(src, vls + b * 4096 + v * 512);
      }
    }
  };

  stage(0, 0);
  for (int kt = 0; kt < SEQ; kt += 64) {
    const int buf = (kt >> 6) & 1;
    if (kt + 64 < SEQ) {
      stage(kt + 64, buf ^ 1);
      asm volatile("s_waitcnt vmcnt(4)" ::: "memory");  // tile kt's 4 loads done
    } else {
      asm volatile("s_waitcnt vmcnt(0)" ::: "memory");  // last tile: drain all
    }
    asm volatile("s_barrier" ::: "memory");  // all waves' tile-kt staging visible
    const __bf16* kb_ = kls + buf * 4096;
    const __bf16* vb_ = vls + buf * 4096;

    // S^T (keys x q) + softmax + P^T pack
#pragma unroll
    for (int kb = 0; kb < 4; kb++) {
      bf16x8 kf0 = *(const bf16x8_al*)(kb_ + (kb * 2) * 512 + lane * 8);
      bf16x8 kf1 = *(const bf16x8_al*)(kb_ + (kb * 2 + 1) * 512 + lane * 8);
      floatx4 s = {};
      s = __builtin_amdgcn_mfma_f32_16x16x32_bf16(kf0, qf0, s, 0, 0, 0);
      s = __builtin_amdgcn_mfma_f32_16x16x32_bf16(kf1, qf1, s, 0, 0, 0);
      bf16x4 pv;
#pragma unroll
      for (int r = 0; r < 4; r++) {
        float p = __expf(s[r]);  // 1/sqrt(D) already folded into K
        lsum += p;
        pv[r] = (__bf16)p;
      }
      // lane holds keys kb*16+lq*4+{0..3} for q=lr -> one b64 store
      int chunk = (kb * 2 + (lq >> 1)) ^ row7;
      *(bf16x4_al*)(plsw + lr * 64 + chunk * 8 + (lq & 1) * 4) = pv;
    }

    // O += P @ V : A-frag P[q=lr][key=kc*32+lq*8+j], B-frag Vt[d][key]
#pragma unroll
    for (int kc = 0; kc < 2; kc++) {
      int chunk = (kc * 4 + lq) ^ row7;
      bf16x8 pf = *(const bf16x8_al*)(plsw + lr * 64 + chunk * 8);
#pragma unroll
      for (int jd = 0; jd < 4; jd++) {
        bf16x8 vf = *(const bf16x8_al*)(vb_ + (jd * 2 + kc) * 512 + lane * 8);
        oacc[jd] = __builtin_amdgcn_mfma_f32_16x16x32_bf16(pf, vf, oacc[jd], 0, 0, 0);
      }
    }
    asm volatile("s_waitcnt lgkmcnt(0)" ::: "memory");  // my LDS reads retired
    asm volatile("s_barrier" ::: "memory");             // WAR: buf free for restage
  }

  // reduce l across the 4 lanes sharing q=lr (lq groups)
  lsum += __shfl_xor(lsum, 16);
  lsum += __shfl_xor(lsum, 32);

  const int b = bh >> 4, h = bh & 15;
#pragma unroll
  for (int r = 0; r < 4; r++) {
    float linv = 1.0f / __shfl(lsum, lq * 4 + r);  // lane q_local holds l(q_local)
    int s = q0 + wave * 16 + lq * 4 + r;
#pragma unroll
    for (int jd = 0; jd < 4; jd++) {
      int d = jd * 16 + lr;
      O[((size_t)b * SEQ + s) * E_DIM + h * D_HEAD + d] = (__bf16)(oacc[jd][r] * linv);
    }
  }
}

// ---------------- launch ----------------
extern "C" void kernel_launch(void* const* d_in, const int* in_sizes, int n_in,
                              void* d_out, int out_size, void* d_ws, size_t ws_size,
                              hipStream_t stream) {
  const float* x  = (const float*)d_in[0];
  const float* Wi = (const float*)d_in[1];
  const float* Ai = (const float*)d_in[2];
  const float* Bi = (const float*)d_in[3];
  const float* Wo = (const float*)d_in[4];
  float* out = (float*)d_out;
  char* ws = (char*)d_ws;

  // workspace layout (bytes)
  __bf16* xcat = (__bf16*)(ws);                  //  4096x1152 bf16   9,437,184
  __bf16* wcat = (__bf16*)(ws + 9437184);        //  3072x1152 bf16   7,077,888
  __bf16* aeff = (__bf16*)(ws + 16515072);       //  128x1024 bf16      262,144
  __bf16* wob  = (__bf16*)(ws + 16777216);       //  1024x1024 bf16   2,097,152
  __bf16* qh   = (__bf16*)(ws + 18874368);       //  [32][2048][64]   8,388,608
  __bf16* kh   = (__bf16*)(ws + 27262976);       //  [32][2048][64]   8,388,608
  __bf16* vt   = (__bf16*)(ws + 35651584);       //  [32][64][2048]   8,388,608
  __bf16* oh   = (__bf16*)(ws + 44040192);       //  4096x1024 bf16   8,388,608

  prep_all<<<8704, 256, 0, stream>>>(x, Wi, Bi, Ai, Wo, xcat, wcat, aeff, wob);

  // t = (x @ Aeff^T)/128 -> xcat cols 1024..1151
  gemm_mfma<1024, K1, E_DIM, 2><<<dim3(32, 1), 256, 0, stream>>>(
      xcat, aeff, nullptr, xcat, nullptr, nullptr);
  // qkv = xcat @ Wcat^T; Q,K -> head layout (K pre-scaled), V -> V^T directly
  gemm_mfma<K1, K1, K1, 1><<<dim3(32, 24), 256, 0, stream>>>(
      xcat, wcat, nullptr, qh, kh, vt);
  attn_kernel<<<dim3(32, 32), 256, 0, stream>>>(qh, kh, vt, oh);
  // final = O @ Wo^T (fp32 out)
  gemm_mfma<1024, 1024, 1024, 0><<<dim3(32, 8), 256, 0, stream>>>(
      oh, wob, out, nullptr, nullptr, nullptr);
}

// Round 5
// 277.756 us; speedup vs baseline: 1.2755x; 1.0056x over previous
//
#include <hip/hip_runtime.h>

// Problem constants
#define E_DIM 1024
#define H_NUM 16
#define D_HEAD 64
#define SEQ 2048
#define BATCH 2
#define NTOK 4096      // BATCH*SEQ
#define R_LORA 128
#define K1 1152        // E_DIM + R_LORA (concat-K for fused LoRA)
#define Q3 3072        // 3*E_DIM
#define K_PRESCALE 0.125f  // 1/sqrt(64), exact in bf16

typedef float floatx4 __attribute__((ext_vector_type(4)));
typedef __bf16 bf16x8 __attribute__((ext_vector_type(8)));
typedef __bf16 bf16x4 __attribute__((ext_vector_type(4)));
typedef bf16x8 bf16x8_al __attribute__((may_alias));
typedef bf16x4 bf16x4_al __attribute__((may_alias));

// async global->LDS, 16B per lane; lds dst must be wave-uniform (HW adds lane*16)
__device__ __forceinline__ void async_cp16(const void* g, void* l) {
  __builtin_amdgcn_global_load_lds(
      (__attribute__((address_space(1))) unsigned int*)(size_t)g,
      (__attribute__((address_space(3))) unsigned int*)l, 16, 0, 0);
}

// ---------------- fused prep kernel (one launch) ----------------
__global__ __launch_bounds__(256) void prep_all(const float* __restrict__ x,
                                                const float* __restrict__ Wi,
                                                const float* __restrict__ Bl,
                                                const float* __restrict__ Ai,
                                                const float* __restrict__ Wo,
                                                __bf16* __restrict__ xcat,
                                                __bf16* __restrict__ wcat,
                                                __bf16* __restrict__ aeff,
                                                __bf16* __restrict__ wob) {
  const int blk = blockIdx.x, t = threadIdx.x;
  if (blk < 4096) {                       // x (4096x1024 fp32) -> xcat cols 0..1023
    int idx = (blk * 256 + t) * 4;
    int n = idx >> 10, k = idx & 1023;
    float4 v = *(const float4*)(x + idx);
    bf16x4 o = {(__bf16)v.x, (__bf16)v.y, (__bf16)v.z, (__bf16)v.w};
    *(bf16x4_al*)(xcat + (size_t)n * K1 + k) = o;
  } else if (blk < 7168) {                // wcat main: row j, fold 3 E-blocks of W_in
    int j = blk - 4096, e = t * 4;
    const float* r = Wi + (size_t)j * Q3;
    float4 a = *(const float4*)(r + e);
    float4 b = *(const float4*)(r + e + 1024);
    float4 c = *(const float4*)(r + e + 2048);
    bf16x4 o = {(__bf16)(a.x + b.x + c.x), (__bf16)(a.y + b.y + c.y),
                (__bf16)(a.z + b.z + c.z), (__bf16)(a.w + b.w + c.w)};
    *(bf16x4_al*)(wcat + (size_t)j * K1 + e) = o;
  } else if (blk < 7552) {                // wcat lora cols: B_in rows
    int idx = (blk - 7168) * 256 + t;     // quad id over 3072x32
    int j = idx >> 5, cq = (idx & 31) * 4;
    float4 v = *(const float4*)(Bl + (size_t)j * R_LORA + cq);
    bf16x4 o = {(__bf16)v.x, (__bf16)v.y, (__bf16)v.z, (__bf16)v.w};
    *(bf16x4_al*)(wcat + (size_t)j * K1 + E_DIM + cq) = o;
  } else if (blk < 7680) {                // aeff: fold 3 E-blocks of A_in
    int r = blk - 7552, e = t * 4;
    const float* rp = Ai + (size_t)r * Q3;
    float4 a = *(const float4*)(rp + e);
    float4 b = *(const float4*)(rp + e + 1024);
    float4 c = *(const float4*)(rp + e + 2048);
    bf16x4 o = {(__bf16)(a.x + b.x + c.x), (__bf16)(a.y + b.y + c.y),
                (__bf16)(a.z + b.z + c.z), (__bf16)(a.w + b.w + c.w)};
    *(bf16x4_al*)(aeff + (size_t)r * E_DIM + e) = o;
  } else {                                // wo cast
    int idx = ((blk - 7680) * 256 + t) * 4;
    float4 v = *(const float4*)(Wo + idx);
    bf16x4 o = {(__bf16)v.x, (__bf16)v.y, (__bf16)v.z, (__bf16)v.w};
    *(bf16x4_al*)(wob + idx) = o;
  }
}

// ---------------- 128x128 MFMA GEMM: D[m][n] = sum_k A[m][k]*B[n][k] ----------------
// EPI 0: fp32 store, ldc=1024 (out-proj)
// EPI 1: qkv scatter; Q,K -> [bh][s][d] scalar (K pre-scaled by 0.125);
//        V -> V^T [bh][d][s] as packed bf16x4 (transpose fused here)
// EPI 2: bf16 store *(1/128) into xcat cols 1024..1151 (LoRA t)
template <int KTOT, int LDA, int LDB, int EPI>
__global__ __launch_bounds__(256) void gemm_mfma(const __bf16* A, const __bf16* Bm,
                                                 float* fOut, __bf16* o0, __bf16* o1,
                                                 __bf16* o2) {
  __shared__ __bf16 lds[8192];  // A-tile 8x(16x32) frag-blocks, then B-tile
  const int t = threadIdx.x;
  const int wave = t >> 6, lane = t & 63;
  const int wm = wave & 1, wn = wave >> 1;
  const int lr = lane & 15, lq = lane >> 4;
  const int m0 = blockIdx.x * 128, n0 = blockIdx.y * 128;

  floatx4 acc[4][4] = {};
  const __bf16* gA = A + (size_t)(m0 + lr) * LDA + lq * 8;
  const __bf16* gB = Bm + (size_t)(n0 + lr) * LDB + lq * 8;

  for (int kk = 0; kk < KTOT; kk += 32) {
    __syncthreads();  // prior frag reads done before overwrite
    async_cp16(gA + (size_t)(wave * 16) * LDA + kk, lds + wave * 512);
    async_cp16(gA + (size_t)((wave + 4) * 16) * LDA + kk, lds + (wave + 4) * 512);
    async_cp16(gB + (size_t)(wave * 16) * LDB + kk, lds + 4096 + wave * 512);
    async_cp16(gB + (size_t)((wave + 4) * 16) * LDB + kk, lds + 4096 + (wave + 4) * 512);
    __syncthreads();  // drains vmcnt -> staging visible
    bf16x8 af[4], bfr[4];
#pragma unroll
    for (int i = 0; i < 4; i++)
      af[i] = *(const bf16x8_al*)(lds + (wm * 4 + i) * 512 + lane * 8);
#pragma unroll
    for (int j = 0; j < 4; j++)
      bfr[j] = *(const bf16x8_al*)(lds + 4096 + (wn * 4 + j) * 512 + lane * 8);
#pragma unroll
    for (int i = 0; i < 4; i++)
#pragma unroll
      for (int j = 0; j < 4; j++)
        acc[i][j] = __builtin_amdgcn_mfma_f32_16x16x32_bf16(af[i], bfr[j], acc[i][j], 0, 0, 0);
  }

#pragma unroll
  for (int i = 0; i < 4; i++)
#pragma unroll
    for (int j = 0; j < 4; j++) {
      const int row0 = m0 + wm * 64 + i * 16 + lq * 4;  // C/D: row = quad*4+reg
      const int col = n0 + wn * 64 + j * 16 + lr;       // C/D: col = lane&15
      if (EPI == 0) {
#pragma unroll
        for (int r = 0; r < 4; r++)
          fOut[(size_t)(row0 + r) * 1024 + col] = acc[i][j][r];
      } else if (EPI == 2) {
#pragma unroll
        for (int r = 0; r < 4; r++)
          o0[(size_t)(row0 + r) * K1 + E_DIM + col] = (__bf16)(acc[i][j][r] * (1.0f / 128.0f));
      } else {
        int part = col >> 10, e = col & 1023, h = e >> 6, d = e & 63;
        int b = row0 >> 11, s = row0 & 2047;
        if (part == 2) {
          // V^T [bh][d][s]: 4 consecutive s in one lane -> packed b64 store
          bf16x4 pv;
#pragma unroll
          for (int r = 0; r < 4; r++) pv[r] = (__bf16)acc[i][j][r];
          *(bf16x4_al*)(o2 + ((size_t)(b * H_NUM + h) * D_HEAD + d) * SEQ + s) = pv;
        } else {
#pragma unroll
          for (int r = 0; r < 4; r++) {
            float v = acc[i][j][r];
            if (part == 1) v *= K_PRESCALE;  // fold softmax 1/sqrt(D) into K
            size_t off = ((size_t)(b * H_NUM + h) * SEQ + (s + r)) * D_HEAD + d;
            (part == 0 ? o0 : o1)[off] = (__bf16)v;
          }
        }
      }
    }
}

// ---------------- flash attention v5: key-split, barrier-free K-loop ----------------
// Block = 2 waves (128 thr), 64 q-rows. Each wave owns a PRIVATE 32-key slice per
// iteration (64 keys/block-iter, 32 iters), staged into per-wave double-buffered
// LDS via global_load_lds; the only waits are per-wave s_waitcnt vmcnt(N) with a
// 1-iteration lookahead — NO s_barrier in the K-loop. S^T = K x Q (A=K rows=keys,
// B=Q cols=q) -> P pack is wave-private LDS round-trip (b64 write, b128 A-frag
// read, XOR-swizzled). Max-free softmax (K pre-scaled 1/8). Partial O (64q x 64d
// fp32/wave) + partial l reduced across the 2 waves once at the end.
__global__ __launch_bounds__(128, 2) void attn_kernel(const __bf16* __restrict__ Q,
                                                      const __bf16* __restrict__ K,
                                                      const __bf16* __restrict__ Vt,
                                                      __bf16* __restrict__ O) {
  // per-wave region (10240 els = 20KB): kbuf[2][2048] | vbuf[2][2048] | pbuf[2048]
  __shared__ __bf16 smem[2 * 10240];  // 40 KB total
  const int t = threadIdx.x, wave = t >> 6, lane = t & 63;
  const int lr = lane & 15, lq = lane >> 4;
  __bf16* kbuf = smem + wave * 10240;
  __bf16* vbuf = kbuf + 4096;
  __bf16* pbuf = vbuf + 4096;
  const int bh = blockIdx.y, q0 = blockIdx.x * 64;
  const size_t hbase = (size_t)bh * SEQ * D_HEAD;
  const __bf16* Kp = K + hbase;
  const __bf16* vtb = Vt + (size_t)bh * D_HEAD * SEQ;
  const int sw = lr & 3;  // P chunk swizzle

  // Q B-frags: qf[g][c] : q = q0+g*16+lr, d = c*32+lq*8
  bf16x8 qf[4][2];
#pragma unroll
  for (int g = 0; g < 4; g++)
#pragma unroll
    for (int c = 0; c < 2; c++)
      qf[g][c] = *(const bf16x8_al*)(Q + hbase + (size_t)(q0 + g * 16 + lr) * D_HEAD +
                                     c * 32 + lq * 8);

  floatx4 oacc[4][4] = {};
  float lsum[4] = {0.0f, 0.0f, 0.0f, 0.0f};

  // stage this wave's 32-key slice for block-iteration it2 into buffer b:
  // K blocks (mg,c): [key=mg*16+lr][d=c*32+lq*8]; V blocks dg: [d=dg*16+lr][k=lq*8]
  auto stage = [&](int it2, int b) {
    const int ktw = it2 * 64 + wave * 32;
    const __bf16* ks = Kp + (size_t)ktw * D_HEAD;
#pragma unroll
    for (int mg = 0; mg < 2; mg++)
#pragma unroll
      for (int c = 0; c < 2; c++)
        async_cp16(ks + (size_t)(mg * 16 + lr) * D_HEAD + c * 32 + lq * 8,
                   kbuf + b * 2048 + (mg * 2 + c) * 512);
#pragma unroll
    for (int dg = 0; dg < 4; dg++)
      async_cp16(vtb + (size_t)(dg * 16 + lr) * SEQ + ktw + lq * 8,
                 vbuf + b * 2048 + dg * 512);
  };

  stage(0, 0);
  for (int it = 0; it < 32; ++it) {
    const int buf = it & 1;
    if (it < 31) {
      stage(it + 1, buf ^ 1);
      asm volatile("s_waitcnt vmcnt(8)" ::: "memory");  // this iter's 8 landed
    } else {
      asm volatile("s_waitcnt vmcnt(0)" ::: "memory");
    }
    const __bf16* kb_ = kbuf + buf * 2048;
    const __bf16* vb_ = vbuf + buf * 2048;

    // K A-frags
    bf16x8 kf[2][2];
#pragma unroll
    for (int mg = 0; mg < 2; mg++)
#pragma unroll
      for (int c = 0; c < 2; c++)
        kf[mg][c] = *(const bf16x8_al*)(kb_ + (mg * 2 + c) * 512 + lane * 8);

    // S^T (keys x q) per q-group, exp, P pack (wave-private)
#pragma unroll
    for (int g = 0; g < 4; g++) {
#pragma unroll
      for (int mg = 0; mg < 2; mg++) {
        floatx4 s = {};
        s = __builtin_amdgcn_mfma_f32_16x16x32_bf16(kf[mg][0], qf[g][0], s, 0, 0, 0);
        s = __builtin_amdgcn_mfma_f32_16x16x32_bf16(kf[mg][1], qf[g][1], s, 0, 0, 0);
        bf16x4 pv;
#pragma unroll
        for (int r = 0; r < 4; r++) {
          float p = __expf(s[r]);  // 1/sqrt(D) folded into K
          lsum[g] += p;
          pv[r] = (__bf16)p;
        }
        // write P[q=g*16+lr][key=mg*16+lq*4+{0..3}] (row stride 32, 16B chunks swizzled)
        int c = (mg * 2 + (lq >> 1)) ^ sw;
        *(bf16x4_al*)(pbuf + (g * 16 + lr) * 32 + c * 8 + (lq & 1) * 4) = pv;
      }
    }

    // O += P @ V (k=32): A-frag P[q=g*16+lr][k=lq*8+j], B-frag V[d][k]
    bf16x8 vf[4];
#pragma unroll
    for (int jd = 0; jd < 4; jd++)
      vf[jd] = *(const bf16x8_al*)(vb_ + jd * 512 + lane * 8);
#pragma unroll
    for (int g = 0; g < 4; g++) {
      bf16x8 pf = *(const bf16x8_al*)(pbuf + (g * 16 + lr) * 32 + (lq ^ sw) * 8);
#pragma unroll
      for (int jd = 0; jd < 4; jd++)
        oacc[g][jd] = __builtin_amdgcn_mfma_f32_16x16x32_bf16(pf, vf[jd], oacc[g][jd], 0, 0, 0);
    }
  }

  // reduce lsum over the 4 lq lanes sharing q=g*16+lr
#pragma unroll
  for (int g = 0; g < 4; g++) {
    lsum[g] += __shfl_xor(lsum[g], 16);
    lsum[g] += __shfl_xor(lsum[g], 32);
  }

  __syncthreads();  // all waves done reading their K-loop LDS; reuse smem for reduction

  // fsm: [wave][64 q][66 pad] fp32 ; lsm: [wave][64 q] fp32
  float* fsm = (float*)smem;
  float* lsm = fsm + 2 * 64 * 66;
#pragma unroll
  for (int g = 0; g < 4; g++)
#pragma unroll
    for (int jd = 0; jd < 4; jd++)
#pragma unroll
      for (int r = 0; r < 4; r++)
        fsm[wave * 4224 + (g * 16 + lq * 4 + r) * 66 + jd * 16 + lr] = oacc[g][jd][r];
  if (lq == 0) {
#pragma unroll
    for (int g = 0; g < 4; g++) lsm[wave * 64 + g * 16 + lr] = lsum[g];
  }
  __syncthreads();

  // each wave: 32 q rows, lane = d; sum the 2 wave-partials, apply 1/l, store
  const int b = bh >> 4, h = bh & 15;
#pragma unroll 4
  for (int i = 0; i < 32; i++) {
    int q = wave * 32 + i;
    float v = fsm[q * 66 + lane] + fsm[4224 + q * 66 + lane];
    float lt = lsm[q] + lsm[64 + q];
    O[((size_t)b * SEQ + (q0 + q)) * E_DIM + h * D_HEAD + lane] = (__bf16)(v / lt);
  }
}

// ---------------- launch ----------------
extern "C" void kernel_launch(void* const* d_in, const int* in_sizes, int n_in,
                              void* d_out, int out_size, void* d_ws, size_t ws_size,
                              hipStream_t stream) {
  const float* x  = (const float*)d_in[0];
  const float* Wi = (const float*)d_in[1];
  const float* Ai = (const float*)d_in[2];
  const float* Bi = (const float*)d_in[3];
  const float* Wo = (const float*)d_in[4];
  float* out = (float*)d_out;
  char* ws = (char*)d_ws;

  // workspace layout (bytes)
  __bf16* xcat = (__bf16*)(ws);                  //  4096x1152 bf16   9,437,184
  __bf16* wcat = (__bf16*)(ws + 9437184);        //  3072x1152 bf16   7,077,888
  __bf16* aeff = (__bf16*)(ws + 16515072);       //  128x1024 bf16      262,144
  __bf16* wob  = (__bf16*)(ws + 16777216);       //  1024x1024 bf16   2,097,152
  __bf16* qh   = (__bf16*)(ws + 18874368);       //  [32][2048][64]   8,388,608
  __bf16* kh   = (__bf16*)(ws + 27262976);       //  [32][2048][64]   8,388,608
  __bf16* vt   = (__bf16*)(ws + 35651584);       //  [32][64][2048]   8,388,608
  __bf16* oh   = (__bf16*)(ws + 44040192);       //  4096x1024 bf16   8,388,608

  prep_all<<<8704, 256, 0, stream>>>(x, Wi, Bi, Ai, Wo, xcat, wcat, aeff, wob);

  // t = (x @ Aeff^T)/128 -> xcat cols 1024..1151
  gemm_mfma<1024, K1, E_DIM, 2><<<dim3(32, 1), 256, 0, stream>>>(
      xcat, aeff, nullptr, xcat, nullptr, nullptr);
  // qkv = xcat @ Wcat^T; Q,K -> head layout (K pre-scaled), V -> V^T directly
  gemm_mfma<K1, K1, K1, 1><<<dim3(32, 24), 256, 0, stream>>>(
      xcat, wcat, nullptr, qh, kh, vt);
  attn_kernel<<<dim3(32, 32), 128, 0, stream>>>(qh, kh, vt, oh);
  // final = O @ Wo^T (fp32 out)
  gemm_mfma<1024, 1024, 1024, 0><<<dim3(32, 8), 256, 0, stream>>>(
      oh, wob, out, nullptr, nullptr, nullptr);
}